// Round 3
// baseline (59.441 us; speedup 1.0000x reference)
//
#include <hip/hip_runtime.h>
#include <math.h>

#define RG 61
#define CG 61
#define NP 3721           // RG*CG
#define NSEG 3722         // NP+1
#define NCLS 10
#define KTOT 12288        // 64*64*3
#define NPATCH 8          // patches per block
#define KS 4              // K-slices (split-K)
#define PAIRS_SLICE 1536  // (KTOT/2)/KS
#define ITERS 6           // PAIRS_SLICE/256
#define THRESHV 0.7f
#define BIGI 0x3FFFFFFF

// ---------------------------------------------------------------------------
// Kernel 1: partial logits, split-K. grid = 61 rowgroups * 8 colgroups * KS.
// Each block: 8 adjacent patches, K-slice of 3072 elements (1536 pairs).
// Partials (80 floats/block) -> ws. Deterministic.
// ---------------------------------------------------------------------------
__global__ __launch_bounds__(256) void wod_logits_part(
    const float* __restrict__ img,   // (1024,1024,3)
    const float* __restrict__ W,     // (12288,10)
    float* __restrict__ part)        // (61*8*KS, 80)
{
    const int tid = threadIdx.x;
    const int blk = blockIdx.x;
    const int ks  = blk & (KS - 1);
    const int g   = blk >> 2;          // r*8 + cg
    const int r   = g >> 3;
    const int cg  = g & 7;
    const int c0  = cg * NPATCH;
    const int np  = (CG - c0) < NPATCH ? (CG - c0) : NPATCH;

    float acc[NPATCH][NCLS];
    #pragma unroll
    for (int p = 0; p < NPATCH; ++p)
        #pragma unroll
        for (int k = 0; k < NCLS; ++k) acc[p][k] = 0.f;

    const float* imgr = img + (16 * r) * 3072 + c0 * 48;

    // pair index pi covers elements e=2*pi, 2*pi+1 ; e=(i*64+j)*3+ch,
    // i = window row, rem = 3*j+ch in [0,192)
    #pragma unroll
    for (int it = 0; it < ITERS; ++it) {
        const int pi  = ks * PAIRS_SLICE + it * 256 + tid;
        const int e   = pi << 1;
        const int i   = e / 192;
        const int rem = e - i * 192;            // even
        const float* wp = W + e * NCLS;          // 80B aligned
        const float4 wa = *(const float4*)(wp);
        const float4 wb = *(const float4*)(wp + 4);
        const float4 wc = *(const float4*)(wp + 8);
        const float4 wd = *(const float4*)(wp + 12);
        const float4 we = *(const float4*)(wp + 16);
        const float w0[NCLS] = {wa.x, wa.y, wa.z, wa.w, wb.x, wb.y, wb.z, wb.w, wc.x, wc.y};
        const float w1[NCLS] = {wc.z, wc.w, wd.x, wd.y, wd.z, wd.w, we.x, we.y, we.z, we.w};
        const float* xb = imgr + i * 3072 + rem;
        #pragma unroll
        for (int p = 0; p < NPATCH; ++p) {
            const int po = (p < np ? p : 0) * 48;   // np uniform -> scalar select, no OOB
            const float2 x = *(const float2*)(xb + po);
            #pragma unroll
            for (int k = 0; k < NCLS; ++k) {
                acc[p][k] = fmaf(x.x, w0[k], acc[p][k]);
                acc[p][k] = fmaf(x.y, w1[k], acc[p][k]);
            }
        }
    }

    // 3-step shuffle: lanes 0 mod 8 hold the sum of their 8-lane group
    #pragma unroll
    for (int p = 0; p < NPATCH; ++p)
        #pragma unroll
        for (int k = 0; k < NCLS; ++k) {
            float v = acc[p][k];
            v += __shfl_down(v, 1);
            v += __shfl_down(v, 2);
            v += __shfl_down(v, 4);
            acc[p][k] = v;
        }

    __shared__ float red[32][81];   // 32 groups x 80 values (+1 pad)
    const int lane = tid & 63, wave = tid >> 6;
    if ((lane & 7) == 0) {
        const int row = wave * 8 + (lane >> 3);
        #pragma unroll
        for (int p = 0; p < NPATCH; ++p)
            #pragma unroll
            for (int k = 0; k < NCLS; ++k)
                red[row][p * NCLS + k] = acc[p][k];
    }
    __syncthreads();
    if (tid < NPATCH * NCLS) {
        float s = 0.f;
        #pragma unroll
        for (int j = 0; j < 32; ++j) s += red[j][tid];
        part[blk * (NPATCH * NCLS) + tid] = s;
    }
}

// ---------------------------------------------------------------------------
// Kernel 2: reduce KS partials + bias + softmax + prob + mask.
// One thread per cell.
// ---------------------------------------------------------------------------
__global__ __launch_bounds__(256) void wod_reduce(
    const float* __restrict__ part,   // (61*8*KS, 80)
    const float* __restrict__ bias,   // (10)
    float* __restrict__ out_prob,     // (61,61,10)
    int* __restrict__ mask)           // (10,3721)
{
    const int cell = blockIdx.x * 256 + threadIdx.x;
    if (cell >= NP) return;
    const int r  = cell / CG;
    const int c  = cell - r * CG;
    const int cg = c >> 3;
    const int p  = c & 7;
    const int gb = ((r * 8 + cg) * KS) * (NPATCH * NCLS) + p * NCLS;

    float lg[NCLS];
    #pragma unroll
    for (int k = 0; k < NCLS; ++k) lg[k] = bias[k];
    #pragma unroll
    for (int ks = 0; ks < KS; ++ks)
        #pragma unroll
        for (int k = 0; k < NCLS; ++k)
            lg[k] += part[gb + ks * (NPATCH * NCLS) + k];

    float m = -1e30f;
    #pragma unroll
    for (int k = 0; k < NCLS; ++k) m = fmaxf(m, lg[k]);
    float ex[NCLS], s = 0.f;
    #pragma unroll
    for (int k = 0; k < NCLS; ++k) { ex[k] = expf(lg[k] - m); s += ex[k]; }
    const float inv = 1.f / s;
    const int base = cell * NCLS;
    #pragma unroll
    for (int k = 0; k < NCLS; ++k) {
        const float pr = ex[k] * inv;
        out_prob[base + k] = pr;
        mask[k * NP + cell] = (pr > THRESHV) ? 1 : 0;
    }
}

// ---------------------------------------------------------------------------
// Kernel 3: connected components (min-label propagation in LDS) + labels +
// boxes + valid, all fused. One block per class. Box extents via LDS atomics,
// two passes (min then max) to stay under the 64KB static LDS limit.
// ---------------------------------------------------------------------------
__global__ __launch_bounds__(256) void wod_cc(
    const int* __restrict__ mask,     // (10,3721)
    float* __restrict__ out_lbl,      // (61,61,10) as float
    float* __restrict__ out_box,      // (10,3722,4)
    float* __restrict__ out_valid)    // (10,3722)
{
    const int k = blockIdx.x;
    const int tid = threadIdx.x;
    __shared__ int lbl[NP];
    __shared__ int ext0[NSEG], ext1[NSEG];
    __shared__ int changed;

    const int* mk = mask + k * NP;
    for (int idx = tid; idx < NP; idx += 256)
        lbl[idx] = mk[idx] ? (idx + 1) : 0;
    if (tid == 0) changed = 0;
    __syncthreads();

    for (;;) {
        for (int idx = tid; idx < NP; idx += 256) {
            int v = lbl[idx];
            if (v) {
                const int rr = idx / CG;
                const int cc = idx - rr * CG;
                int best = v;
                if (rr > 0)      { int n = lbl[idx - CG]; if (n && n < best) best = n; }
                if (rr < RG - 1) { int n = lbl[idx + CG]; if (n && n < best) best = n; }
                if (cc > 0)      { int n = lbl[idx - 1];  if (n && n < best) best = n; }
                if (cc < CG - 1) { int n = lbl[idx + 1];  if (n && n < best) best = n; }
                if (best < v) { lbl[idx] = best; changed = 1; }
            }
        }
        __syncthreads();
        const bool stop = (changed == 0);
        __syncthreads();           // all reads of `changed` done before reset
        if (stop) break;
        if (tid == 0) changed = 0;
        __syncthreads();
    }

    // labels out (transposed to (r,c,k))
    for (int idx = tid; idx < NP; idx += 256)
        out_lbl[idx * NCLS + k] = (float)lbl[idx];

    float* boxk = out_box + k * NSEG * 4;
    float* valk = out_valid + k * NSEG;

    // pass 1: rmin / cmin
    for (int s = tid; s < NSEG; s += 256) { ext0[s] = BIGI; ext1[s] = BIGI; }
    __syncthreads();
    for (int idx = tid; idx < NP; idx += 256) {
        const int v = lbl[idx];
        if (v) {
            const int rr = idx / CG, cc = idx - rr * CG;
            atomicMin(&ext0[v], rr);
            atomicMin(&ext1[v], cc);
        }
    }
    __syncthreads();
    for (int s = tid; s < NSEG; s += 256) {
        const bool valid = (s > 0) && (ext0[s] != BIGI);
        boxk[s * 4 + 0] = valid ? (float)(ext0[s] - 1) : -1.f;
        boxk[s * 4 + 1] = valid ? (float)(ext1[s] - 1) : -1.f;
        valk[s] = valid ? 1.f : 0.f;
    }
    __syncthreads();

    // pass 2: rmax / cmax
    for (int s = tid; s < NSEG; s += 256) { ext0[s] = -1; ext1[s] = -1; }
    __syncthreads();
    for (int idx = tid; idx < NP; idx += 256) {
        const int v = lbl[idx];
        if (v) {
            const int rr = idx / CG, cc = idx - rr * CG;
            atomicMax(&ext0[v], rr);
            atomicMax(&ext1[v], cc);
        }
    }
    __syncthreads();
    for (int s = tid; s < NSEG; s += 256) {
        const bool valid = (s > 0) && (ext0[s] >= 0);
        boxk[s * 4 + 2] = valid ? (float)(ext0[s] + 1) : -1.f;
        boxk[s * 4 + 3] = valid ? (float)(ext1[s] + 1) : -1.f;
    }
}

// ---------------------------------------------------------------------------
extern "C" void kernel_launch(void* const* d_in, const int* in_sizes, int n_in,
                              void* d_out, int out_size, void* d_ws, size_t ws_size,
                              hipStream_t stream) {
    (void)in_sizes; (void)n_in; (void)out_size; (void)ws_size;
    const float* img = (const float*)d_in[0];
    const float* W   = (const float*)d_in[1];
    const float* b   = (const float*)d_in[2];

    float* out       = (float*)d_out;
    float* out_prob  = out;                       // 37210
    float* out_lbl   = out + 37210;               // 37210
    float* out_box   = out + 74420;               // 148880
    float* out_valid = out + 223300;              // 37220

    int*   mask = (int*)d_ws;                     // 10*3721
    float* part = (float*)d_ws + NCLS * NP;       // 61*8*KS*80 floats

    hipLaunchKernelGGL(wod_logits_part, dim3(RG * 8 * KS), dim3(256), 0, stream,
                       img, W, part);
    hipLaunchKernelGGL(wod_reduce, dim3((NP + 255) / 256), dim3(256), 0, stream,
                       part, b, out_prob, mask);
    hipLaunchKernelGGL(wod_cc, dim3(NCLS), dim3(256), 0, stream,
                       mask, out_lbl, out_box, out_valid);
}

// Round 4
// 51.993 us; speedup vs baseline: 1.1432x; 1.1432x over previous
//
#include <hip/hip_runtime.h>
#include <math.h>

#define RG 61
#define CG 61
#define NP 3721           // RG*CG
#define NSEG 3722         // NP+1
#define NCLS 10
#define KTOT 12288        // 64*64*3
#define NPATCH 8          // patches per block
#define KS 2              // K-slices
#define PAIRS_SLICE 3072  // (KTOT/2)/KS
#define ITERS 12          // PAIRS_SLICE/256
#define THRESHV 0.7f
#define BIGI 0x3FFFFFFF

// ---------------------------------------------------------------------------
// Kernel 1: partial logits. grid = KS * 488 (ks-major: co-resident blocks
// share the same W K-phase). Block: 8 adjacent patches (c0 clamped to 53 so
// all 8 always valid), explicit A/B register prefetch: issue the 13 loads of
// iter n+1, then 320 FMAs of iter n (640 issue-cycles hide ~400cyc L2 lat).
// ---------------------------------------------------------------------------
#define DECLBUF(S) float4 wa##S, wb##S, wc##S, wd##S, we##S; \
                   float2 x0##S, x1##S, x2##S, x3##S, x4##S, x5##S, x6##S, x7##S;

#define LOADW(S, IT) { \
    const int e_   = (ksbase + (IT) * 256 + tid) << 1; \
    const int i_   = e_ / 192; \
    const int rem_ = e_ - i_ * 192; \
    const float* wp_ = W + e_ * NCLS;          /* 80B aligned */ \
    wa##S = *(const float4*)(wp_); \
    wb##S = *(const float4*)(wp_ + 4); \
    wc##S = *(const float4*)(wp_ + 8); \
    wd##S = *(const float4*)(wp_ + 12); \
    we##S = *(const float4*)(wp_ + 16); \
    const float* xb_ = imgr + i_ * 3072 + rem_; \
    x0##S = *(const float2*)(xb_); \
    x1##S = *(const float2*)(xb_ + 48); \
    x2##S = *(const float2*)(xb_ + 96); \
    x3##S = *(const float2*)(xb_ + 144); \
    x4##S = *(const float2*)(xb_ + 192); \
    x5##S = *(const float2*)(xb_ + 240); \
    x6##S = *(const float2*)(xb_ + 288); \
    x7##S = *(const float2*)(xb_ + 336); \
}

#define FMAS(S) { \
    const float w0_[NCLS] = {wa##S.x, wa##S.y, wa##S.z, wa##S.w, \
                             wb##S.x, wb##S.y, wb##S.z, wb##S.w, wc##S.x, wc##S.y}; \
    const float w1_[NCLS] = {wc##S.z, wc##S.w, wd##S.x, wd##S.y, \
                             wd##S.z, wd##S.w, we##S.x, we##S.y, we##S.z, we##S.w}; \
    const float2 xs_[NPATCH] = {x0##S, x1##S, x2##S, x3##S, x4##S, x5##S, x6##S, x7##S}; \
    _Pragma("unroll") \
    for (int p_ = 0; p_ < NPATCH; ++p_) { \
        _Pragma("unroll") \
        for (int k_ = 0; k_ < NCLS; ++k_) { \
            acc[p_][k_] = fmaf(xs_[p_].x, w0_[k_], acc[p_][k_]); \
            acc[p_][k_] = fmaf(xs_[p_].y, w1_[k_], acc[p_][k_]); \
        } \
    } \
}

__global__ __launch_bounds__(256, 2) void wod_logits_part(
    const float* __restrict__ img,   // (1024,1024,3)
    const float* __restrict__ W,     // (12288,10)
    float* __restrict__ part)        // (KS*488, 80)
{
    const int tid = threadIdx.x;
    const int blk = blockIdx.x;
    const int ks  = (blk >= 488) ? 1 : 0;
    const int g   = blk - ks * 488;    // r*8 + cg
    const int r   = g >> 3;
    const int cg  = g & 7;
    const int c0  = (cg < 7) ? cg * 8 : 53;   // clamp: all 8 patches valid

    const int ksbase = ks * PAIRS_SLICE;
    const float* imgr = img + (16 * r) * 3072 + c0 * 48;

    float acc[NPATCH][NCLS];
    #pragma unroll
    for (int p = 0; p < NPATCH; ++p)
        #pragma unroll
        for (int k = 0; k < NCLS; ++k) acc[p][k] = 0.f;

    DECLBUF(A)
    DECLBUF(B)

    LOADW(A, 0)
    #pragma unroll 1
    for (int t = 0; t < ITERS / 2; ++t) {
        LOADW(B, 2 * t + 1)
        FMAS(A)
        if (t < ITERS / 2 - 1) { LOADW(A, 2 * t + 2) }
        FMAS(B)
    }

    // 3-step shuffle: lanes 0 mod 8 hold the sum of their 8-lane group
    #pragma unroll
    for (int p = 0; p < NPATCH; ++p)
        #pragma unroll
        for (int k = 0; k < NCLS; ++k) {
            float v = acc[p][k];
            v += __shfl_down(v, 1);
            v += __shfl_down(v, 2);
            v += __shfl_down(v, 4);
            acc[p][k] = v;
        }

    __shared__ float red[32][81];   // 32 groups x 80 values (+1 pad)
    const int lane = tid & 63, wave = tid >> 6;
    if ((lane & 7) == 0) {
        const int row = wave * 8 + (lane >> 3);
        #pragma unroll
        for (int p = 0; p < NPATCH; ++p)
            #pragma unroll
            for (int k = 0; k < NCLS; ++k)
                red[row][p * NCLS + k] = acc[p][k];
    }
    __syncthreads();
    if (tid < NPATCH * NCLS) {
        float s = 0.f;
        #pragma unroll
        for (int j = 0; j < 32; ++j) s += red[j][tid];
        part[blk * (NPATCH * NCLS) + tid] = s;
    }
}

// ---------------------------------------------------------------------------
// Kernel 2: reduce KS partials + bias + softmax + prob + mask.
// One thread per cell; reads the unique (cg,p) covering each c.
// ---------------------------------------------------------------------------
__global__ __launch_bounds__(256) void wod_reduce(
    const float* __restrict__ part,   // (KS*488, 80)
    const float* __restrict__ bias,   // (10)
    float* __restrict__ out_prob,     // (61,61,10)
    int* __restrict__ mask)           // (10,3721)
{
    const int cell = blockIdx.x * 256 + threadIdx.x;
    if (cell >= NP) return;
    const int r  = cell / CG;
    const int c  = cell - r * CG;
    int cg = c >> 3; if (cg > 7) cg = 7;
    const int c0 = (cg < 7) ? cg * 8 : 53;
    const int p  = c - c0;
    const int g  = r * 8 + cg;
    const int gb0 = g * (NPATCH * NCLS) + p * NCLS;
    const int gb1 = (488 + g) * (NPATCH * NCLS) + p * NCLS;

    float lg[NCLS];
    #pragma unroll
    for (int k = 0; k < NCLS; ++k)
        lg[k] = bias[k] + part[gb0 + k] + part[gb1 + k];

    float m = -1e30f;
    #pragma unroll
    for (int k = 0; k < NCLS; ++k) m = fmaxf(m, lg[k]);
    float ex[NCLS], s = 0.f;
    #pragma unroll
    for (int k = 0; k < NCLS; ++k) { ex[k] = expf(lg[k] - m); s += ex[k]; }
    const float inv = 1.f / s;
    const int base = cell * NCLS;
    #pragma unroll
    for (int k = 0; k < NCLS; ++k) {
        const float pr = ex[k] * inv;
        out_prob[base + k] = pr;
        mask[k * NP + cell] = (pr > THRESHV) ? 1 : 0;
    }
}

// ---------------------------------------------------------------------------
// Kernel 3: connected components (min-label propagation in LDS) + labels +
// boxes + valid, all fused. One block per class.
// ---------------------------------------------------------------------------
__global__ __launch_bounds__(256) void wod_cc(
    const int* __restrict__ mask,     // (10,3721)
    float* __restrict__ out_lbl,      // (61,61,10) as float
    float* __restrict__ out_box,      // (10,3722,4)
    float* __restrict__ out_valid)    // (10,3722)
{
    const int k = blockIdx.x;
    const int tid = threadIdx.x;
    __shared__ int lbl[NP];
    __shared__ int ext0[NSEG], ext1[NSEG];
    __shared__ int changed;

    const int* mk = mask + k * NP;
    for (int idx = tid; idx < NP; idx += 256)
        lbl[idx] = mk[idx] ? (idx + 1) : 0;
    if (tid == 0) changed = 0;
    __syncthreads();

    for (;;) {
        for (int idx = tid; idx < NP; idx += 256) {
            int v = lbl[idx];
            if (v) {
                const int rr = idx / CG;
                const int cc = idx - rr * CG;
                int best = v;
                if (rr > 0)      { int n = lbl[idx - CG]; if (n && n < best) best = n; }
                if (rr < RG - 1) { int n = lbl[idx + CG]; if (n && n < best) best = n; }
                if (cc > 0)      { int n = lbl[idx - 1];  if (n && n < best) best = n; }
                if (cc < CG - 1) { int n = lbl[idx + 1];  if (n && n < best) best = n; }
                if (best < v) { lbl[idx] = best; changed = 1; }
            }
        }
        __syncthreads();
        const bool stop = (changed == 0);
        __syncthreads();           // all reads of `changed` done before reset
        if (stop) break;
        if (tid == 0) changed = 0;
        __syncthreads();
    }

    // labels out (transposed to (r,c,k))
    for (int idx = tid; idx < NP; idx += 256)
        out_lbl[idx * NCLS + k] = (float)lbl[idx];

    float* boxk = out_box + k * NSEG * 4;
    float* valk = out_valid + k * NSEG;

    // pass 1: rmin / cmin
    for (int s = tid; s < NSEG; s += 256) { ext0[s] = BIGI; ext1[s] = BIGI; }
    __syncthreads();
    for (int idx = tid; idx < NP; idx += 256) {
        const int v = lbl[idx];
        if (v) {
            const int rr = idx / CG, cc = idx - rr * CG;
            atomicMin(&ext0[v], rr);
            atomicMin(&ext1[v], cc);
        }
    }
    __syncthreads();
    for (int s = tid; s < NSEG; s += 256) {
        const bool valid = (s > 0) && (ext0[s] != BIGI);
        boxk[s * 4 + 0] = valid ? (float)(ext0[s] - 1) : -1.f;
        boxk[s * 4 + 1] = valid ? (float)(ext1[s] - 1) : -1.f;
        valk[s] = valid ? 1.f : 0.f;
    }
    __syncthreads();

    // pass 2: rmax / cmax
    for (int s = tid; s < NSEG; s += 256) { ext0[s] = -1; ext1[s] = -1; }
    __syncthreads();
    for (int idx = tid; idx < NP; idx += 256) {
        const int v = lbl[idx];
        if (v) {
            const int rr = idx / CG, cc = idx - rr * CG;
            atomicMax(&ext0[v], rr);
            atomicMax(&ext1[v], cc);
        }
    }
    __syncthreads();
    for (int s = tid; s < NSEG; s += 256) {
        const bool valid = (s > 0) && (ext0[s] >= 0);
        boxk[s * 4 + 2] = valid ? (float)(ext0[s] + 1) : -1.f;
        boxk[s * 4 + 3] = valid ? (float)(ext1[s] + 1) : -1.f;
    }
}

// ---------------------------------------------------------------------------
extern "C" void kernel_launch(void* const* d_in, const int* in_sizes, int n_in,
                              void* d_out, int out_size, void* d_ws, size_t ws_size,
                              hipStream_t stream) {
    (void)in_sizes; (void)n_in; (void)out_size; (void)ws_size;
    const float* img = (const float*)d_in[0];
    const float* W   = (const float*)d_in[1];
    const float* b   = (const float*)d_in[2];

    float* out       = (float*)d_out;
    float* out_prob  = out;                       // 37210
    float* out_lbl   = out + 37210;               // 37210
    float* out_box   = out + 74420;               // 148880
    float* out_valid = out + 223300;              // 37220

    int*   mask = (int*)d_ws;                     // 10*3721
    float* part = (float*)d_ws + NCLS * NP;       // KS*488*80 floats

    hipLaunchKernelGGL(wod_logits_part, dim3(KS * 488), dim3(256), 0, stream,
                       img, W, part);
    hipLaunchKernelGGL(wod_reduce, dim3((NP + 255) / 256), dim3(256), 0, stream,
                       part, b, out_prob, mask);
    hipLaunchKernelGGL(wod_cc, dim3(NCLS), dim3(256), 0, stream,
                       mask, out_lbl, out_box, out_valid);
}

// Round 5
// 50.958 us; speedup vs baseline: 1.1665x; 1.0203x over previous
//
#include <hip/hip_runtime.h>
#include <math.h>

#define RG 61
#define CG 61
#define NP 3721           // RG*CG
#define NSEG 3722         // NP+1
#define NCLS 10
#define KTOT 12288        // 64*64*3
#define NPATCH 8          // patches per block
#define KS 2              // K-slices
#define PAIRS_SLICE 3072  // (KTOT/2)/KS
#define ITERS 12          // PAIRS_SLICE/256
#define THRESHV 0.7f
#define BIGI 0x3FFFFFFF

// ---------------------------------------------------------------------------
// Kernel 1: partial logits. grid = KS * 488. Block: 8 adjacent patches
// (c0 clamped to 53 so all 8 valid). Explicit A/B register prefetch, with
// __builtin_amdgcn_sched_barrier(0) walls so the scheduler CANNOT fold the
// pipeline: iter n+1's 13 loads are issued before iter n's 320 FMA-cycles,
// and the auto waitcnt lands after them (latency hidden in-wave).
// ---------------------------------------------------------------------------
#define DECLBUF(S) float4 wa##S, wb##S, wc##S, wd##S, we##S; \
                   float2 x0##S, x1##S, x2##S, x3##S, x4##S, x5##S, x6##S, x7##S;

#define LOADW(S, IT) { \
    const int e_   = (ksbase + (IT) * 256 + tid) << 1; \
    const int i_   = e_ / 192; \
    const int rem_ = e_ - i_ * 192; \
    const float* wp_ = W + e_ * NCLS;          /* 80B aligned */ \
    wa##S = *(const float4*)(wp_); \
    wb##S = *(const float4*)(wp_ + 4); \
    wc##S = *(const float4*)(wp_ + 8); \
    wd##S = *(const float4*)(wp_ + 12); \
    we##S = *(const float4*)(wp_ + 16); \
    const float* xb_ = imgr + i_ * 3072 + rem_; \
    x0##S = *(const float2*)(xb_); \
    x1##S = *(const float2*)(xb_ + 48); \
    x2##S = *(const float2*)(xb_ + 96); \
    x3##S = *(const float2*)(xb_ + 144); \
    x4##S = *(const float2*)(xb_ + 192); \
    x5##S = *(const float2*)(xb_ + 240); \
    x6##S = *(const float2*)(xb_ + 288); \
    x7##S = *(const float2*)(xb_ + 336); \
}

#define FMAS(S) { \
    const float w0_[NCLS] = {wa##S.x, wa##S.y, wa##S.z, wa##S.w, \
                             wb##S.x, wb##S.y, wb##S.z, wb##S.w, wc##S.x, wc##S.y}; \
    const float w1_[NCLS] = {wc##S.z, wc##S.w, wd##S.x, wd##S.y, \
                             wd##S.z, wd##S.w, we##S.x, we##S.y, we##S.z, we##S.w}; \
    const float2 xs_[NPATCH] = {x0##S, x1##S, x2##S, x3##S, x4##S, x5##S, x6##S, x7##S}; \
    _Pragma("unroll") \
    for (int p_ = 0; p_ < NPATCH; ++p_) { \
        _Pragma("unroll") \
        for (int k_ = 0; k_ < NCLS; ++k_) { \
            acc[p_][k_] = fmaf(xs_[p_].x, w0_[k_], acc[p_][k_]); \
            acc[p_][k_] = fmaf(xs_[p_].y, w1_[k_], acc[p_][k_]); \
        } \
    } \
}

#define SBAR() __builtin_amdgcn_sched_barrier(0)

__global__ __launch_bounds__(256, 2) void wod_logits_part(
    const float* __restrict__ img,   // (1024,1024,3)
    const float* __restrict__ W,     // (12288,10)
    float* __restrict__ part)        // (KS*488, 80)
{
    const int tid = threadIdx.x;
    const int blk = blockIdx.x;
    const int ks  = (blk >= 488) ? 1 : 0;
    const int g   = blk - ks * 488;    // r*8 + cg
    const int r   = g >> 3;
    const int cg  = g & 7;
    const int c0  = (cg < 7) ? cg * 8 : 53;   // clamp: all 8 patches valid

    const int ksbase = ks * PAIRS_SLICE;
    const float* imgr = img + (16 * r) * 3072 + c0 * 48;

    float acc[NPATCH][NCLS];
    #pragma unroll
    for (int p = 0; p < NPATCH; ++p)
        #pragma unroll
        for (int k = 0; k < NCLS; ++k) acc[p][k] = 0.f;

    DECLBUF(A)
    DECLBUF(B)

    LOADW(A, 0)
    #pragma unroll 1
    for (int t = 0; t < ITERS / 2; ++t) {
        SBAR();
        LOADW(B, 2 * t + 1)      // issue 13 loads of pair-iter 2t+1
        SBAR();
        FMAS(A)                  // 320 FMA-cycles cover their latency
        SBAR();
        if (t < ITERS / 2 - 1) { LOADW(A, 2 * t + 2) }
        SBAR();
        FMAS(B)
        SBAR();
    }

    // 3-step shuffle: lanes 0 mod 8 hold the sum of their 8-lane group
    #pragma unroll
    for (int p = 0; p < NPATCH; ++p)
        #pragma unroll
        for (int k = 0; k < NCLS; ++k) {
            float v = acc[p][k];
            v += __shfl_down(v, 1);
            v += __shfl_down(v, 2);
            v += __shfl_down(v, 4);
            acc[p][k] = v;
        }

    __shared__ float red[32][81];   // 32 groups x 80 values (+1 pad)
    const int lane = tid & 63, wave = tid >> 6;
    if ((lane & 7) == 0) {
        const int row = wave * 8 + (lane >> 3);
        #pragma unroll
        for (int p = 0; p < NPATCH; ++p)
            #pragma unroll
            for (int k = 0; k < NCLS; ++k)
                red[row][p * NCLS + k] = acc[p][k];
    }
    __syncthreads();
    if (tid < NPATCH * NCLS) {
        float s = 0.f;
        #pragma unroll
        for (int j = 0; j < 32; ++j) s += red[j][tid];
        part[blk * (NPATCH * NCLS) + tid] = s;
    }
}

// ---------------------------------------------------------------------------
// Kernel 2: reduce KS partials + bias + softmax + prob + mask.
// ---------------------------------------------------------------------------
__global__ __launch_bounds__(256) void wod_reduce(
    const float* __restrict__ part,   // (KS*488, 80)
    const float* __restrict__ bias,   // (10)
    float* __restrict__ out_prob,     // (61,61,10)
    int* __restrict__ mask)           // (10,3721)
{
    const int cell = blockIdx.x * 256 + threadIdx.x;
    if (cell >= NP) return;
    const int r  = cell / CG;
    const int c  = cell - r * CG;
    int cg = c >> 3; if (cg > 7) cg = 7;
    const int c0 = (cg < 7) ? cg * 8 : 53;
    const int p  = c - c0;
    const int g  = r * 8 + cg;
    const int gb0 = g * (NPATCH * NCLS) + p * NCLS;
    const int gb1 = (488 + g) * (NPATCH * NCLS) + p * NCLS;

    float lg[NCLS];
    #pragma unroll
    for (int k = 0; k < NCLS; ++k)
        lg[k] = bias[k] + part[gb0 + k] + part[gb1 + k];

    float m = -1e30f;
    #pragma unroll
    for (int k = 0; k < NCLS; ++k) m = fmaxf(m, lg[k]);
    float ex[NCLS], s = 0.f;
    #pragma unroll
    for (int k = 0; k < NCLS; ++k) { ex[k] = expf(lg[k] - m); s += ex[k]; }
    const float inv = 1.f / s;
    const int base = cell * NCLS;
    #pragma unroll
    for (int k = 0; k < NCLS; ++k) {
        const float pr = ex[k] * inv;
        out_prob[base + k] = pr;
        mask[k * NP + cell] = (pr > THRESHV) ? 1 : 0;
    }
}

// ---------------------------------------------------------------------------
// Kernel 3: connected components (min-label propagation in LDS) + labels +
// boxes + valid, all fused. One block per class.
// ---------------------------------------------------------------------------
__global__ __launch_bounds__(256) void wod_cc(
    const int* __restrict__ mask,     // (10,3721)
    float* __restrict__ out_lbl,      // (61,61,10) as float
    float* __restrict__ out_box,      // (10,3722,4)
    float* __restrict__ out_valid)    // (10,3722)
{
    const int k = blockIdx.x;
    const int tid = threadIdx.x;
    __shared__ int lbl[NP];
    __shared__ int ext0[NSEG], ext1[NSEG];
    __shared__ int changed;

    const int* mk = mask + k * NP;
    for (int idx = tid; idx < NP; idx += 256)
        lbl[idx] = mk[idx] ? (idx + 1) : 0;
    if (tid == 0) changed = 0;
    __syncthreads();

    for (;;) {
        for (int idx = tid; idx < NP; idx += 256) {
            int v = lbl[idx];
            if (v) {
                const int rr = idx / CG;
                const int cc = idx - rr * CG;
                int best = v;
                if (rr > 0)      { int n = lbl[idx - CG]; if (n && n < best) best = n; }
                if (rr < RG - 1) { int n = lbl[idx + CG]; if (n && n < best) best = n; }
                if (cc > 0)      { int n = lbl[idx - 1];  if (n && n < best) best = n; }
                if (cc < CG - 1) { int n = lbl[idx + 1];  if (n && n < best) best = n; }
                if (best < v) { lbl[idx] = best; changed = 1; }
            }
        }
        __syncthreads();
        const bool stop = (changed == 0);
        __syncthreads();           // all reads of `changed` done before reset
        if (stop) break;
        if (tid == 0) changed = 0;
        __syncthreads();
    }

    // labels out (transposed to (r,c,k))
    for (int idx = tid; idx < NP; idx += 256)
        out_lbl[idx * NCLS + k] = (float)lbl[idx];

    float* boxk = out_box + k * NSEG * 4;
    float* valk = out_valid + k * NSEG;

    // pass 1: rmin / cmin
    for (int s = tid; s < NSEG; s += 256) { ext0[s] = BIGI; ext1[s] = BIGI; }
    __syncthreads();
    for (int idx = tid; idx < NP; idx += 256) {
        const int v = lbl[idx];
        if (v) {
            const int rr = idx / CG, cc = idx - rr * CG;
            atomicMin(&ext0[v], rr);
            atomicMin(&ext1[v], cc);
        }
    }
    __syncthreads();
    for (int s = tid; s < NSEG; s += 256) {
        const bool valid = (s > 0) && (ext0[s] != BIGI);
        boxk[s * 4 + 0] = valid ? (float)(ext0[s] - 1) : -1.f;
        boxk[s * 4 + 1] = valid ? (float)(ext1[s] - 1) : -1.f;
        valk[s] = valid ? 1.f : 0.f;
    }
    __syncthreads();

    // pass 2: rmax / cmax
    for (int s = tid; s < NSEG; s += 256) { ext0[s] = -1; ext1[s] = -1; }
    __syncthreads();
    for (int idx = tid; idx < NP; idx += 256) {
        const int v = lbl[idx];
        if (v) {
            const int rr = idx / CG, cc = idx - rr * CG;
            atomicMax(&ext0[v], rr);
            atomicMax(&ext1[v], cc);
        }
    }
    __syncthreads();
    for (int s = tid; s < NSEG; s += 256) {
        const bool valid = (s > 0) && (ext0[s] >= 0);
        boxk[s * 4 + 2] = valid ? (float)(ext0[s] + 1) : -1.f;
        boxk[s * 4 + 3] = valid ? (float)(ext1[s] + 1) : -1.f;
    }
}

// ---------------------------------------------------------------------------
extern "C" void kernel_launch(void* const* d_in, const int* in_sizes, int n_in,
                              void* d_out, int out_size, void* d_ws, size_t ws_size,
                              hipStream_t stream) {
    (void)in_sizes; (void)n_in; (void)out_size; (void)ws_size;
    const float* img = (const float*)d_in[0];
    const float* W   = (const float*)d_in[1];
    const float* b   = (const float*)d_in[2];

    float* out       = (float*)d_out;
    float* out_prob  = out;                       // 37210
    float* out_lbl   = out + 37210;               // 37210
    float* out_box   = out + 74420;               // 148880
    float* out_valid = out + 223300;              // 37220

    int*   mask = (int*)d_ws;                     // 10*3721
    float* part = (float*)d_ws + NCLS * NP;       // KS*488*80 floats

    hipLaunchKernelGGL(wod_logits_part, dim3(KS * 488), dim3(256), 0, stream,
                       img, W, part);
    hipLaunchKernelGGL(wod_reduce, dim3((NP + 255) / 256), dim3(256), 0, stream,
                       part, b, out_prob, mask);
    hipLaunchKernelGGL(wod_cc, dim3(NCLS), dim3(256), 0, stream,
                       mask, out_lbl, out_box, out_valid);
}